// Round 1
// baseline (337.265 us; speedup 1.0000x reference)
//
#include <hip/hip_runtime.h>

// Problem constants: B=4, S=256, V=50257, D=768
#define BATCH 4
#define SEQ   256
#define VOCAB 50257
#define DIM   768

constexpr int  ROWS   = BATCH * SEQ;                 // 1024
constexpr long TOTAL  = (long)ROWS * VOCAB;          // 51,463,168 (divisible by 4)
constexpr long TOTAL4 = TOTAL / 4;                   // 12,865,792
constexpr int  DIM4   = DIM / 4;                     // 192

// Grid-stride scan config: 2048 blocks x 256 thr = 524288 threads = 32 waves/CU.
constexpr int  SCAN_BLOCKS  = 2048;
constexpr int  SCAN_THREADS = 256;
constexpr long SCAN_STRIDE  = (long)SCAN_BLOCKS * SCAN_THREADS;  // 524288

// Rare-path resolver: called only when a float4 contains the (single) 1.0 of a row.
__device__ __forceinline__ void resolve_hit(float4 v, long i, int* __restrict__ idx) {
    if (v.x != 0.0f || v.y != 0.0f || v.z != 0.0f || v.w != 0.0f) {
        float vals[4] = {v.x, v.y, v.z, v.w};
        long base = i * 4;
        // A float4 can straddle a row boundary (VOCAB odd) -> resolve each
        // component independently. Exactly one nonzero per row total, so plain
        // stores (no atomics) are race-free.
        #pragma unroll
        for (int j = 0; j < 4; ++j) {
            if (vals[j] != 0.0f) {
                long flat = base + j;
                int row = (int)(flat / VOCAB);     // rare path: div is fine
                int col = (int)(flat - (long)row * VOCAB);
                idx[row] = col;
            }
        }
    }
}

// Kernel 1: grid-stride scan of the dense one_hot, 4 independent float4 loads
// in flight per thread per iteration (MLP), lane-consecutive addresses at every
// load instruction (perfect coalescing).
__global__ __launch_bounds__(SCAN_THREADS) void find_idx_kernel(
    const float4* __restrict__ oh, int* __restrict__ idx) {
    long i = (long)blockIdx.x * SCAN_THREADS + threadIdx.x;

    // Main loop: 6 full iterations for every thread (no per-load bounds checks).
    for (; i + 3 * SCAN_STRIDE < TOTAL4; i += 4 * SCAN_STRIDE) {
        float4 a = oh[i];
        float4 b = oh[i +     SCAN_STRIDE];
        float4 c = oh[i + 2 * SCAN_STRIDE];
        float4 d = oh[i + 3 * SCAN_STRIDE];
        resolve_hit(a, i,                   idx);
        resolve_hit(b, i +     SCAN_STRIDE, idx);
        resolve_hit(c, i + 2 * SCAN_STRIDE, idx);
        resolve_hit(d, i + 3 * SCAN_STRIDE, idx);
    }
    // Tail: at most one extra float4 per thread (282,880 remaining < SCAN_STRIDE).
    for (; i < TOTAL4; i += SCAN_STRIDE) {
        float4 v = oh[i];
        resolve_hit(v, i, idx);
    }
}

// Kernel 2: gather weight[idx[row]] -> out[row], float4-coalesced. ~6 MB moved,
// negligible vs the scan.
__global__ __launch_bounds__(DIM4) void gather_kernel(
    const float4* __restrict__ weight, const int* __restrict__ idx,
    float4* __restrict__ out) {
    int row = blockIdx.x;
    int t   = threadIdx.x;            // 0..191
    int src = idx[row];
    out[(long)row * DIM4 + t] = weight[(long)src * DIM4 + t];
}

extern "C" void kernel_launch(void* const* d_in, const int* in_sizes, int n_in,
                              void* d_out, int out_size, void* d_ws, size_t ws_size,
                              hipStream_t stream) {
    const float4* one_hot = (const float4*)d_in[0];   // [B,S,V] f32
    const float4* weight  = (const float4*)d_in[1];   // [V,D]  f32
    float4* out = (float4*)d_out;                     // [B,S,D] f32
    int* idx = (int*)d_ws;                            // ROWS ints of scratch

    // Phase 1: grid-stride scan, full occupancy (2048 blocks = 8 blocks/CU).
    find_idx_kernel<<<SCAN_BLOCKS, SCAN_THREADS, 0, stream>>>(one_hot, idx);

    // Phase 2: gather rows.
    gather_kernel<<<ROWS, DIM4, 0, stream>>>(weight, idx, out);
}

// Round 2
// 334.365 us; speedup vs baseline: 1.0087x; 1.0087x over previous
//
#include <hip/hip_runtime.h>

// Problem constants: B=4, S=256, V=50257, D=768
#define BATCH 4
#define SEQ   256
#define VOCAB 50257
#define DIM   768

constexpr int  ROWS   = BATCH * SEQ;                 // 1024
constexpr long TOTAL  = (long)ROWS * VOCAB;          // 51,463,168 elements
constexpr long TOTAL4 = TOTAL / 4;                   // 12,865,792 float4s
constexpr int  DIM4   = DIM / 4;                     // 192 float4s per row

// Grid config: 2048 blocks x 256 thr = 8 blocks/CU = full 32 waves/CU.
constexpr int  BLOCKS  = 2048;
constexpr int  THREADS = 256;
constexpr long STRIDE  = (long)BLOCKS * THREADS;     // 524,288
// TOTAL4 / STRIDE = 24.54 -> every thread does 24 full strided loads (6 x 4-unroll)
// plus one clamped tail load (all lanes stay active -> wave ops remain safe).
constexpr int  FULL_ITERS = 6;                       // 6*4 = 24 strides

// Rare path: a wave found >=1 nonzero among one strided load "q".
// All 64 lanes are active here (callers guarantee wave-uniform entry).
// For each hitting lane, broadcast its 4 dwords; for each nonzero element,
// the whole wave copies weight[col] -> out[row] (3 float4 per lane, coalesced).
// Each row has exactly one nonzero -> exactly one wave writes each out row.
__device__ __forceinline__ void handle_hits(
    unsigned or_q, uint4 v, long i_q, int lane,
    const float4* __restrict__ w4, float4* __restrict__ out4) {
    unsigned long long m = __ballot(or_q != 0u);
    while (m) {
        int src = __ffsll(m) - 1;
        m &= m - 1;
        // i is lane-consecutive within the wave: recover src lane's index
        // arithmetically (no shfl needed for the index itself).
        long i_src = i_q - lane + src;
        unsigned vv0 = __shfl(v.x, src);
        unsigned vv1 = __shfl(v.y, src);
        unsigned vv2 = __shfl(v.z, src);
        unsigned vv3 = __shfl(v.w, src);
        unsigned vv[4] = {vv0, vv1, vv2, vv3};
        long base = i_src * 4;
        #pragma unroll
        for (int j = 0; j < 4; ++j) {
            if (vv[j] != 0u) {          // wave-uniform branch (post-shfl)
                long flat = base + j;
                int row = (int)(flat / VOCAB);   // rare path: div is fine
                int col = (int)(flat - (long)row * VOCAB);
                const float4* srcw = w4  + (long)col * DIM4;
                float4*       dst  = out4 + (long)row * DIM4;
                #pragma unroll
                for (int c = 0; c < 3; ++c)      // 192 = 3 * 64 lanes
                    dst[c * 64 + lane] = srcw[c * 64 + lane];
            }
        }
    }
}

// Single fused kernel: grid-stride scan of one_hot (integer OR-tree detection,
// ~20 VALU inst per 4KB/wave => ~3% of HBM time) + in-wave gather on hit.
__global__ __launch_bounds__(THREADS) void fused_embed_kernel(
    const uint4* __restrict__ oh, const float4* __restrict__ w4,
    float4* __restrict__ out4) {
    const int lane = threadIdx.x & 63;
    long i = (long)blockIdx.x * THREADS + threadIdx.x;

    #pragma unroll 1
    for (int it = 0; it < FULL_ITERS; ++it) {
        uint4 a = oh[i];
        uint4 b = oh[i +     STRIDE];
        uint4 c = oh[i + 2 * STRIDE];
        uint4 d = oh[i + 3 * STRIDE];
        unsigned oa = a.x | a.y | a.z | a.w;
        unsigned ob = b.x | b.y | b.z | b.w;
        unsigned oc = c.x | c.y | c.z | c.w;
        unsigned od = d.x | d.y | d.z | d.w;
        // Wave-uniform rare-path entry: all 64 lanes enter together so the
        // ballot/shfl/gather inside handle_hits see the full wave.
        if (__builtin_expect(__ballot((oa | ob | oc | od) != 0u) != 0ull, 0)) {
            handle_hits(oa, a, i,              lane, w4, out4);
            handle_hits(ob, b, i +     STRIDE, lane, w4, out4);
            handle_hits(oc, c, i + 2 * STRIDE, lane, w4, out4);
            handle_hits(od, d, i + 3 * STRIDE, lane, w4, out4);
        }
        i += 4 * STRIDE;
    }

    // Clamped tail (25th stride): keep every lane active so wave ops stay
    // correct; out-of-range lanes load element 0 and force or=0.
    {
        bool safe = i < TOTAL4;
        long addr = safe ? i : 0;
        uint4 a = oh[addr];
        unsigned oa = safe ? (a.x | a.y | a.z | a.w) : 0u;
        if (__builtin_expect(__ballot(oa != 0u) != 0ull, 0)) {
            handle_hits(oa, a, i, lane, w4, out4);
        }
    }
}

extern "C" void kernel_launch(void* const* d_in, const int* in_sizes, int n_in,
                              void* d_out, int out_size, void* d_ws, size_t ws_size,
                              hipStream_t stream) {
    const uint4*  one_hot = (const uint4*)d_in[0];    // [B,S,V] f32 (bit view)
    const float4* weight  = (const float4*)d_in[1];   // [V,D]  f32
    float4* out = (float4*)d_out;                     // [B,S,D] f32

    // One launch: scan + gather fused; no workspace, no inter-kernel dependency.
    fused_embed_kernel<<<BLOCKS, THREADS, 0, stream>>>(one_hot, weight, out);
}